// Round 8
// baseline (500.503 us; speedup 1.0000x reference)
//
#include <hip/hip_runtime.h>

// B=256, N=196, C=256, H=8, KD=32, VD=64, Q=49, R=14
#define EPS 1e-5f
#define QK_SCALE 0.17677669529663687f

typedef __attribute__((ext_vector_type(8))) short bf16x8;   // 8 bf16 = 4 VGPRs
typedef __attribute__((ext_vector_type(4))) float f32x4;

__device__ inline unsigned short bf16_rne(float f) {
    unsigned int u = __float_as_uint(f);
    u = u + 0x7FFFu + ((u >> 16) & 1u);
    return (unsigned short)(u >> 16);
}
__device__ inline float bf16_f(unsigned short s) {
    return __uint_as_float(((unsigned int)s) << 16);
}
__device__ inline void split1(float v, unsigned short& hi, unsigned short& lo) {
    hi = bf16_rne(v); lo = bf16_rne(v - bf16_f(hi));
}

// ---- packed bf16 split via v_cvt_pk_bf16_f32 (RNE, same rounding as bf16_rne)
__device__ inline unsigned int cvtpk_bf16(float a, float b) {
    unsigned int r;
    asm("v_cvt_pk_bf16_f32 %0, %1, %2" : "=v"(r) : "v"(a), "v"(b));
    return r;   // low16 = bf16(a), high16 = bf16(b)
}
__device__ inline void split2pk(float a, float b, unsigned int& h, unsigned int& l) {
    h = cvtpk_bf16(a, b);
    float ra = a - __uint_as_float(h << 16);
    float rb = b - __uint_as_float(h & 0xFFFF0000u);
    l = cvtpk_bf16(ra, rb);
}
__device__ inline void split4pk(float4 v, uint2& h, uint2& l) {
    unsigned int h01, l01, h23, l23;
    split2pk(v.x, v.y, h01, l01);
    split2pk(v.z, v.w, h23, l23);
    h.x = h01; h.y = h23; l.x = l01; l.y = l23;
}

#define MFMA16(a, b, c) __builtin_amdgcn_mfma_f32_16x16x32_bf16((a), (b), (c), 0, 0, 0)

// ---------- prep: split weights to bf16 hi/lo planes in ws
__global__ __launch_bounds__(256)
void prep_split(const float* __restrict__ kv_w, const float* __restrict__ q_w,
                const float* __restrict__ pw,
                unsigned short* __restrict__ wb_hi, unsigned short* __restrict__ wb_lo,
                unsigned short* __restrict__ pw_hi, unsigned short* __restrict__ pw_lo)
{
    int i = blockIdx.x * 256 + threadIdx.x;
    if (i < 262144) {
        int c = i & 255, j = (i >> 8) & 127, h = i >> 15;
        float v = (j < 96) ? kv_w[(h * 96 + j) * 256 + c]
                           : q_w[(h * 32 + (j - 96)) * 256 + c];
        unsigned short hi, lo; split1(v, hi, lo);
        wb_hi[i] = hi; wb_lo[i] = lo;
    } else {
        int p = i - 262144;
        if (p < 196608) {
            float v = pw[p];
            unsigned short hi, lo; split1(v, hi, lo);
            pw_hi[p] = hi; pw_lo[p] = lo;
        }
    }
}

// ---------- fused attn R8: 2 HEADS PER BLOCK. grid (256, 4); 1024 thr; 1 block/CU.
// GEMM1 = 208 x 256 (heads 2hp, 2hp+1); x staged ONCE for both heads:
//   x LDS reads/head -31%, x staging+splits+barriers/head -50%, x HBM fetch -50%.
// Then per head sequentially: epilogue -> QK+softmax -> PV (buffers reused).
// LDS s_big 160,384 B:  P[64][232]x2 | K[208][40]x2 | Q[52][40]x2 | V[64][232]x2
//   GEMM1 overlay: x[208][72]x2 (29952 sh) + w[256][72]x2 (36864 sh) = 66816 < 80192
__global__ __launch_bounds__(1024, 4)
void levit_fused_attn(const float* __restrict__ x,
                      const unsigned short* __restrict__ wb_hi,
                      const unsigned short* __restrict__ wb_lo,
                      const float* __restrict__ kv_g, const float* __restrict__ kv_b,
                      const float* __restrict__ kv_m, const float* __restrict__ kv_v,
                      const float* __restrict__ q_g, const float* __restrict__ q_b,
                      const float* __restrict__ q_m, const float* __restrict__ q_v,
                      const float* __restrict__ attn_bias,
                      unsigned short* __restrict__ ao_hi,
                      unsigned short* __restrict__ ao_lo)
{
    __shared__ __align__(16) unsigned short s_big[80192];
    __shared__ float bias_s[392];              // [2][196]

    unsigned short* s_phi = s_big;             // [64][232]
    unsigned short* s_plo = s_big + 14848;
    unsigned short* s_khi = s_big + 29696;     // [208][40]
    unsigned short* s_klo = s_big + 38016;
    unsigned short* s_qhi = s_big + 46336;     // [52][40]
    unsigned short* s_qlo = s_big + 48416;
    unsigned short* s_vhi = s_big + 50496;     // [64][232] (V^T)
    unsigned short* s_vlo = s_big + 65344;     // ends 80192
    // staging overlay (dead after GEMM1 final barrier)
    unsigned short* st_xhi = s_big;            // [208][72]
    unsigned short* st_xlo = s_big + 14976;    // ends 29952
    unsigned short* st_whi = s_big + 29952;    // [256][72]
    unsigned short* st_wlo = s_big + 48384;    // ends 66816

    const int t = threadIdx.x;
    const int b = blockIdx.x;       // linear id = b + 256*hp -> same-b pairs share an XCD
    const int hp = blockIdx.y;      // head pair: heads 2hp, 2hp+1

    const int l = t & 63;
    const int w = t >> 6;           // 16 waves
    const int rg = w & 3;           // n-tiles rt = rg + 4i (i<4, rt<13)
    const int cg = w >> 2;          // per-head j-tiles ct = 2cg, 2cg+1
    const int lrow = l & 15;
    const int kg = (l >> 4) * 8;
    const int g4 = (l >> 4) * 4;

    // ---- staging geometry: x units (row, 8col): 1664 units over 1024 thr x 2 its
    const int x0row = t >> 3,  x0c8 = (t & 7) * 8;           // rows 0..127
    const int u1 = t + 1024;
    const int x1row = u1 >> 3, x1c8 = (u1 & 7) * 8;          // rows 128..207
    const bool xv1 = (t < 640);
    // W: 256 rows x 8 units = 2048 units over 1024 thr x 2 its (rows wj0, wj0+128)
    const int wj0 = t >> 3, wc8 = (t & 7) * 8;
    const unsigned short* wsrc_hi = wb_hi + (hp * 256 + wj0) * 256 + wc8;
    const unsigned short* wsrc_lo = wb_lo + (hp * 256 + wj0) * 256 + wc8;
    const float* xbase = x + b * 196 * 256;
    const float4 f4z = {0.f, 0.f, 0.f, 0.f};

    float4 x0a, x0b, x1a, x1b;
    bf16x8 wrh0, wrl0, wrh1, wrl1;

    // prologue: issue chunk-0 loads, overlap with init
    x0a = (x0row < 196) ? *(const float4*)&xbase[x0row * 256 + x0c8]     : f4z;
    x0b = (x0row < 196) ? *(const float4*)&xbase[x0row * 256 + x0c8 + 4] : f4z;
    x1a = f4z; x1b = f4z;
    if (xv1 && x1row < 196) {
        x1a = *(const float4*)&xbase[x1row * 256 + x1c8];
        x1b = *(const float4*)&xbase[x1row * 256 + x1c8 + 4];
    }
    wrh0 = *(const bf16x8*)&wsrc_hi[0];
    wrl0 = *(const bf16x8*)&wsrc_lo[0];
    wrh1 = *(const bf16x8*)&wsrc_hi[128 * 256];
    wrl1 = *(const bf16x8*)&wsrc_lo[128 * 256];

    if (t < 392) {
        int h2 = (t >= 196), idx = t - 196 * h2;
        bias_s[t] = attn_bias[(2 * hp + h2) * 196 + idx];
    }

    f32x4 acc[4][4];   // [i][2h+ctl]
    #pragma unroll
    for (int i = 0; i < 4; ++i)
        #pragma unroll
        for (int k = 0; k < 4; ++k) acc[i][k] = (f32x4){0,0,0,0};

    // prologue store of chunk 0
    {
        uint2 ha, la, hb, lb;
        split4pk(x0a, ha, la); split4pk(x0b, hb, lb);
        *(uint4*)&st_xhi[x0row * 72 + x0c8] = (uint4){ha.x, ha.y, hb.x, hb.y};
        *(uint4*)&st_xlo[x0row * 72 + x0c8] = (uint4){la.x, la.y, lb.x, lb.y};
        if (xv1) {
            split4pk(x1a, ha, la); split4pk(x1b, hb, lb);
            *(uint4*)&st_xhi[x1row * 72 + x1c8] = (uint4){ha.x, ha.y, hb.x, hb.y};
            *(uint4*)&st_xlo[x1row * 72 + x1c8] = (uint4){la.x, la.y, lb.x, lb.y};
        }
    }
    *(bf16x8*)&st_whi[wj0 * 72 + wc8] = wrh0;
    *(bf16x8*)&st_wlo[wj0 * 72 + wc8] = wrl0;
    *(bf16x8*)&st_whi[(wj0 + 128) * 72 + wc8] = wrh1;
    *(bf16x8*)&st_wlo[(wj0 + 128) * 72 + wc8] = wrl1;
    __syncthreads();

    // ---------------- GEMM1: [208 x 256] = x @ [W(2hp); W(2hp+1)]^T, MFMA(W, x)
    for (int s = 0; s < 4; ++s) {
        if (s < 3) {                 // issue next BK=64 chunk's loads (covered by MFMA)
            const int kcn = 64 * (s + 1);
            x0a = (x0row < 196) ? *(const float4*)&xbase[x0row * 256 + kcn + x0c8]     : f4z;
            x0b = (x0row < 196) ? *(const float4*)&xbase[x0row * 256 + kcn + x0c8 + 4] : f4z;
            x1a = f4z; x1b = f4z;
            if (xv1 && x1row < 196) {
                x1a = *(const float4*)&xbase[x1row * 256 + kcn + x1c8];
                x1b = *(const float4*)&xbase[x1row * 256 + kcn + x1c8 + 4];
            }
            wrh0 = *(const bf16x8*)&wsrc_hi[kcn];
            wrl0 = *(const bf16x8*)&wsrc_lo[kcn];
            wrh1 = *(const bf16x8*)&wsrc_hi[128 * 256 + kcn];
            wrl1 = *(const bf16x8*)&wsrc_lo[128 * 256 + kcn];
        }

        #pragma unroll
        for (int sub = 0; sub < 2; ++sub) {
            const int ko = 32 * sub + kg;
            bf16x8 wfh[4], wfl[4];
            #pragma unroll
            for (int h2 = 0; h2 < 2; ++h2)
                #pragma unroll
                for (int ctl = 0; ctl < 2; ++ctl) {
                    const int k = 2 * h2 + ctl;
                    const int jr = h2 * 128 + 16 * (2 * cg + ctl) + lrow;
                    wfh[k] = *(const bf16x8*)&st_whi[jr * 72 + ko];
                    wfl[k] = *(const bf16x8*)&st_wlo[jr * 72 + ko];
                }
            #pragma unroll
            for (int i = 0; i < 4; ++i) {
                const int rt = rg + 4 * i;
                if (rt < 13) {                       // wave-uniform
                    const int arow = 16 * rt + lrow;
                    bf16x8 xh = *(const bf16x8*)&st_xhi[arow * 72 + ko];
                    bf16x8 xl = *(const bf16x8*)&st_xlo[arow * 72 + ko];
                    #pragma unroll
                    for (int k = 0; k < 4; ++k) {
                        acc[i][k] = MFMA16(wfh[k], xh, acc[i][k]);
                        acc[i][k] = MFMA16(wfh[k], xl, acc[i][k]);
                        acc[i][k] = MFMA16(wfl[k], xh, acc[i][k]);
                    }
                }
            }
        }

        if (s < 3) {
            // pre-split next chunk (loads arrived under the MFMA phase) -> regs
            uint4 h0, l0, h1, l1;
            {
                uint2 ha, la, hb, lb;
                split4pk(x0a, ha, la); split4pk(x0b, hb, lb);
                h0 = (uint4){ha.x, ha.y, hb.x, hb.y};
                l0 = (uint4){la.x, la.y, lb.x, lb.y};
                if (xv1) {
                    split4pk(x1a, ha, la); split4pk(x1b, hb, lb);
                    h1 = (uint4){ha.x, ha.y, hb.x, hb.y};
                    l1 = (uint4){la.x, la.y, lb.x, lb.y};
                }
            }
            __syncthreads();         // all waves done reading staging
            *(uint4*)&st_xhi[x0row * 72 + x0c8] = h0;
            *(uint4*)&st_xlo[x0row * 72 + x0c8] = l0;
            if (xv1) {
                *(uint4*)&st_xhi[x1row * 72 + x1c8] = h1;
                *(uint4*)&st_xlo[x1row * 72 + x1c8] = l1;
            }
            *(bf16x8*)&st_whi[wj0 * 72 + wc8] = wrh0;
            *(bf16x8*)&st_wlo[wj0 * 72 + wc8] = wrl0;
            *(bf16x8*)&st_whi[(wj0 + 128) * 72 + wc8] = wrh1;
            *(bf16x8*)&st_wlo[(wj0 + 128) * 72 + wc8] = wrl1;
            __syncthreads();         // next buffer ready
        }
    }
    __syncthreads();   // staging dead -> safe to write K/Q/V

    // ---------------- per-head: epilogue -> QK+softmax -> PV
    #pragma unroll
    for (int h = 0; h < 2; ++h) {
        const int head = 2 * hp + h;

        // epilogue: norm (params direct from global) + wide scatter
        #pragma unroll
        for (int ctl = 0; ctl < 2; ++ctl) {
            const int ct = 2 * cg + ctl;
            const int k = 2 * h + ctl;
            const int j0 = 16 * ct + g4;
            float4 gv, bv, mv, vv;
            if (ct < 6) {
                const int col = head * 96 + j0;
                gv = *(const float4*)&kv_g[col]; bv = *(const float4*)&kv_b[col];
                mv = *(const float4*)&kv_m[col]; vv = *(const float4*)&kv_v[col];
            } else {
                const int col = head * 32 + (j0 - 96);
                gv = *(const float4*)&q_g[col]; bv = *(const float4*)&q_b[col];
                mv = *(const float4*)&q_m[col]; vv = *(const float4*)&q_v[col];
            }
            const float iv0 = gv.x * rsqrtf(vv.x + EPS), be0 = bv.x - mv.x * iv0;
            const float iv1 = gv.y * rsqrtf(vv.y + EPS), be1 = bv.y - mv.y * iv1;
            const float iv2 = gv.z * rsqrtf(vv.z + EPS), be2 = bv.z - mv.z * iv2;
            const float iv3 = gv.w * rsqrtf(vv.w + EPS), be3 = bv.w - mv.w * iv3;
            #pragma unroll
            for (int i = 0; i < 4; ++i) {
                const int rt = rg + 4 * i;
                if (rt < 13) {
                    const int n = 16 * rt + lrow;
                    if (n < 196) {
                        float v0 = acc[i][k][0] * iv0 + be0;
                        float v1 = acc[i][k][1] * iv1 + be1;
                        float v2 = acc[i][k][2] * iv2 + be2;
                        float v3 = acc[i][k][3] * iv3 + be3;
                        unsigned int h01, l01, h23, l23;
                        split2pk(v0, v1, h01, l01);
                        split2pk(v2, v3, h23, l23);
                        if (ct < 2) {                    // K[n][kd]: wide 8B
                            *(uint2*)&s_khi[n * 40 + j0] = (uint2){h01, h23};
                            *(uint2*)&s_klo[n * 40 + j0] = (uint2){l01, l23};
                        } else if (ct < 6) {             // V^T[vd][n]: narrow (accepted)
                            const int vd0 = j0 - 32;
                            s_vhi[(vd0+0) * 232 + n] = (unsigned short)h01;
                            s_vhi[(vd0+1) * 232 + n] = (unsigned short)(h01 >> 16);
                            s_vhi[(vd0+2) * 232 + n] = (unsigned short)h23;
                            s_vhi[(vd0+3) * 232 + n] = (unsigned short)(h23 >> 16);
                            s_vlo[(vd0+0) * 232 + n] = (unsigned short)l01;
                            s_vlo[(vd0+1) * 232 + n] = (unsigned short)(l01 >> 16);
                            s_vlo[(vd0+2) * 232 + n] = (unsigned short)l23;
                            s_vlo[(vd0+3) * 232 + n] = (unsigned short)(l23 >> 16);
                        } else {                         // Q[qi][kd]: wide 8B
                            const int a = n / 28, rem = n - 28 * a;
                            if (rem < 14 && !(rem & 1)) {
                                const int qi = a * 7 + (rem >> 1);
                                *(uint2*)&s_qhi[qi * 40 + (j0 - 96)] = (uint2){h01, h23};
                                *(uint2*)&s_qlo[qi * 40 + (j0 - 96)] = (uint2){l01, l23};
                            }
                        }
                    }
                }
            }
        }
        if (h == 0) {
            // zero V^T pad cols 196..231 (once; h1 writes only cols<196)
            for (int i = t; i < 64 * 36; i += 1024) {
                int r = i / 36, c = 196 + i % 36;
                s_vhi[r * 232 + c] = 0; s_vlo[r * 232 + c] = 0;
            }
        }
        __syncthreads();   // K/Q/V ready

        // ---- QK^T swapped (waves 0-3) | P-pad zero h==0 (idle waves)
        if (w < 4) {
            const int mt = w;
            bf16x8 qh = *(const bf16x8*)&s_qhi[(16 * mt + lrow) * 40 + kg];
            bf16x8 ql = *(const bf16x8*)&s_qlo[(16 * mt + lrow) * 40 + kg];
            f32x4 sv[13];
            #pragma unroll
            for (int nt = 0; nt < 13; ++nt) {
                bf16x8 kh = *(const bf16x8*)&s_khi[(16 * nt + lrow) * 40 + kg];
                bf16x8 kl = *(const bf16x8*)&s_klo[(16 * nt + lrow) * 40 + kg];
                f32x4 a = {0.f, 0.f, 0.f, 0.f};
                a = MFMA16(kh, qh, a);
                a = MFMA16(kh, ql, a);
                a = MFMA16(kl, qh, a);
                sv[nt] = a;
            }
            const int m = 16 * mt + lrow;          // this lane's output row
            const int mq = m < 49 ? m : 48;
            const int yq = (mq / 7) * 2, xq2 = (mq % 7) * 2;
            const float* bias_h = bias_s + h * 196;

            float lmax = -3.0e38f;
            #pragma unroll
            for (int nt = 0; nt < 13; ++nt) {
                #pragma unroll
                for (int reg = 0; reg < 4; ++reg) {
                    const int n = 16 * nt + g4 + reg;
                    float sc;
                    if (n < 196) {
                        const int yk = n / 14, xk = n - 14 * yk;
                        int d0 = yq - yk;  d0 = d0 < 0 ? -d0 : d0;
                        int d1 = xq2 - xk; d1 = d1 < 0 ? -d1 : d1;
                        sc = sv[nt][reg] * QK_SCALE + bias_h[d0 * 14 + d1];
                    } else {
                        sc = -1.0e30f;
                    }
                    sv[nt][reg] = sc;
                    lmax = fmaxf(lmax, sc);
                }
            }
            lmax = fmaxf(lmax, __shfl_xor(lmax, 16, 64));
            lmax = fmaxf(lmax, __shfl_xor(lmax, 32, 64));
            float rsum = 0.f;
            #pragma unroll
            for (int nt = 0; nt < 13; ++nt)
                #pragma unroll
                for (int reg = 0; reg < 4; ++reg) {
                    float p = __expf(sv[nt][reg] - lmax);
                    sv[nt][reg] = p;
                    rsum += p;
                }
            rsum += __shfl_xor(rsum, 16, 64);
            rsum += __shfl_xor(rsum, 32, 64);
            const float rinv = 1.f / rsum;
            #pragma unroll
            for (int nt = 0; nt < 13; ++nt) {      // wide row-major P writes
                unsigned int h01, l01, h23, l23;
                split2pk(sv[nt][0] * rinv, sv[nt][1] * rinv, h01, l01);
                split2pk(sv[nt][2] * rinv, sv[nt][3] * rinv, h23, l23);
                const int o = m * 232 + 16 * nt + g4;
                *(uint2*)&s_phi[o] = (uint2){h01, h23};
                *(uint2*)&s_plo[o] = (uint2){l01, l23};
            }
        } else if (h == 0) {
            // zero P pad cols 208..231 (idle waves; persists for h1)
            for (int i = t - 256; i < 64 * 24; i += 768) {
                int r = i / 24, c = 208 + i % 24;
                s_phi[r * 232 + c] = 0; s_plo[r * 232 + c] = 0;
            }
        }
        __syncthreads();   // P (+pads) ready

        // ---- PV swapped: O^T = MFMA(V^T, P); wide ao stores
        {
            const int mtv = w & 3;
            const int ntv = w >> 2;
            f32x4 pacc = {0.f, 0.f, 0.f, 0.f};
            #pragma unroll
            for (int s = 0; s < 7; ++s) {
                bf16x8 ph = *(const bf16x8*)&s_phi[(16 * mtv + lrow) * 232 + 32 * s + kg];
                bf16x8 pl = *(const bf16x8*)&s_plo[(16 * mtv + lrow) * 232 + 32 * s + kg];
                bf16x8 vh = *(const bf16x8*)&s_vhi[(16 * ntv + lrow) * 232 + 32 * s + kg];
                bf16x8 vl = *(const bf16x8*)&s_vlo[(16 * ntv + lrow) * 232 + 32 * s + kg];
                pacc = MFMA16(vh, ph, pacc);
                pacc = MFMA16(vh, pl, pacc);
                pacc = MFMA16(vl, ph, pacc);
            }
            const int m = 16 * mtv + lrow;        // lane's output row
            if (m < 49) {
                const int vd0 = 16 * ntv + g4;    // consecutive vd quad
                float hs0, hs1, hs2, hs3;
                { float v = pacc[0]; hs0 = v * fminf(fmaxf(v + 3.f, 0.f), 6.f) * (1.f/6.f); }
                { float v = pacc[1]; hs1 = v * fminf(fmaxf(v + 3.f, 0.f), 6.f) * (1.f/6.f); }
                { float v = pacc[2]; hs2 = v * fminf(fmaxf(v + 3.f, 0.f), 6.f) * (1.f/6.f); }
                { float v = pacc[3]; hs3 = v * fminf(fmaxf(v + 3.f, 0.f), 6.f) * (1.f/6.f); }
                unsigned int h01, l01, h23, l23;
                split2pk(hs0, hs1, h01, l01);
                split2pk(hs2, hs3, h23, l23);
                const int idx = ((b * 49 + m) * 8 + head) * 64 + vd0;
                *(uint2*)&ao_hi[idx] = (uint2){h01, h23};
                *(uint2*)&ao_lo[idx] = (uint2){l01, l23};
            }
        }
        if (h == 0) __syncthreads();   // PV h0 reads done before h1 epilogue overwrites
    }
}

// ---------- proj (R4-proven): pipelined reg-prefetch, A-sharing tile map, swapped MFMA
__global__ __launch_bounds__(512, 6)
void levit_proj(const unsigned short* __restrict__ ao_hi,
                const unsigned short* __restrict__ ao_lo,
                const unsigned short* __restrict__ pw_hi,
                const unsigned short* __restrict__ pw_lo,
                const float* __restrict__ pg, const float* __restrict__ pb,
                const float* __restrict__ pm, const float* __restrict__ pv,
                float* __restrict__ out)
{
    __shared__ __align__(16) unsigned short s_a[2 * 64 * 72];   // hi | lo
    __shared__ __align__(16) unsigned short s_w[2 * 96 * 72];

    unsigned short* s_ahi = s_a;          unsigned short* s_alo = s_a + 64 * 72;
    unsigned short* s_whi = s_w;          unsigned short* s_wlo = s_w + 96 * 72;

    const int t = threadIdx.x;
    const int b = blockIdx.x;
    const int cg = blockIdx.y;            // 96-col group (0..3)
    const int l = t & 63;
    const int w = t >> 6;
    const int lrow = l & 15;
    const int kg = (l >> 4) * 8;
    const int g4 = (l >> 4) * 4;

    // ---- staging geometry (fixed across kc)
    const int ar = t >> 3, ac8 = (t & 7) * 8;
    const bool aval = (ar < 49);
    const long aoff = (long)(b * 49 + ar) * 512 + ac8;
    int wpl_[3], wr_[3], wc_[3];
    #pragma unroll
    for (int it = 0; it < 3; ++it) {
        int f = t + 512 * it;
        int plane = (f >= 768), rem = plane ? f - 768 : f;
        wpl_[it] = plane; wr_[it] = rem >> 3; wc_[it] = (rem & 7) * 8;
    }

    bf16x8 pa_h = {}, pa_l = {}, pwr[3];

    // prologue: load kc=0 chunk
    if (aval) {
        pa_h = *(const bf16x8*)&ao_hi[aoff];
        pa_l = *(const bf16x8*)&ao_lo[aoff];
    }
    #pragma unroll
    for (int it = 0; it < 3; ++it) {
        const unsigned short* src = wpl_[it] ? pw_lo : pw_hi;
        pwr[it] = *(const bf16x8*)&src[(cg * 96 + wr_[it]) * 512 + wc_[it]];
    }
    *(bf16x8*)&s_ahi[ar * 72 + ac8] = pa_h;
    *(bf16x8*)&s_alo[ar * 72 + ac8] = pa_l;
    #pragma unroll
    for (int it = 0; it < 3; ++it) {
        unsigned short* dst = wpl_[it] ? s_wlo : s_whi;
        *(bf16x8*)&dst[wr_[it] * 72 + wc_[it]] = pwr[it];
    }
    __syncthreads();

    const int mt = w & 3;
    const int ntb = 3 * (w >> 2);

    f32x4 acc[3] = {{0.f,0.f,0.f,0.f},{0.f,0.f,0.f,0.f},{0.f,0.f,0.f,0.f}};

    for (int s = 0; s < 8; ++s) {
        if (s < 7) {                  // prefetch next kc chunk into regs
            const int kc = 64 * (s + 1);
            pa_h = (bf16x8){}; pa_l = (bf16x8){};
            if (aval) {
                pa_h = *(const bf16x8*)&ao_hi[aoff + kc];
                pa_l = *(const bf16x8*)&ao_lo[aoff + kc];
            }
            #pragma unroll
            for (int it = 0; it < 3; ++it) {
                const unsigned short* src = wpl_[it] ? pw_lo : pw_hi;
                pwr[it] = *(const bf16x8*)&src[(cg * 96 + wr_[it]) * 512 + kc + wc_[it]];
            }
        }

        #pragma unroll
        for (int sub = 0; sub < 2; ++sub) {
            const int ko = 32 * sub + kg;
            bf16x8 ah = *(const bf16x8*)&s_ahi[(16 * mt + lrow) * 72 + ko];
            bf16x8 al = *(const bf16x8*)&s_alo[(16 * mt + lrow) * 72 + ko];
            #pragma unroll
            for (int i = 0; i < 3; ++i) {
                const int nt = ntb + i;
                bf16x8 bh = *(const bf16x8*)&s_whi[(16 * nt + lrow) * 72 + ko];
                bf16x8 bl = *(const bf16x8*)&s_wlo[(16 * nt + lrow) * 72 + ko];
                acc[i] = MFMA16(bh, ah, acc[i]);
                acc[i] = MFMA16(bl, ah, acc[i]);
                acc[i] = MFMA16(bh, al, acc[i]);
            }
        }

        if (s < 7) {
            __syncthreads();
            *(bf16x8*)&s_ahi[ar * 72 + ac8] = pa_h;
            *(bf16x8*)&s_alo[ar * 72 + ac8] = pa_l;
            #pragma unroll
            for (int it = 0; it < 3; ++it) {
                unsigned short* dst = wpl_[it] ? s_wlo : s_whi;
                *(bf16x8*)&dst[wr_[it] * 72 + wc_[it]] = pwr[it];
            }
            __syncthreads();
        }
    }

    const int r = 16 * mt + lrow;
    if (r < 49) {
        #pragma unroll
        for (int i = 0; i < 3; ++i) {
            const int nt = ntb + i;
            const int o0 = cg * 96 + 16 * nt + g4;
            const float4 g4v = *(const float4*)&pg[o0];
            const float4 v4v = *(const float4*)&pv[o0];
            const float4 b4v = *(const float4*)&pb[o0];
            const float4 m4v = *(const float4*)&pm[o0];
            float iv0 = g4v.x * rsqrtf(v4v.x + EPS);
            float iv1 = g4v.y * rsqrtf(v4v.y + EPS);
            float iv2 = g4v.z * rsqrtf(v4v.z + EPS);
            float iv3 = g4v.w * rsqrtf(v4v.w + EPS);
            float4 ov;
            ov.x = acc[i][0] * iv0 + (b4v.x - m4v.x * iv0);
            ov.y = acc[i][1] * iv1 + (b4v.y - m4v.y * iv1);
            ov.z = acc[i][2] * iv2 + (b4v.z - m4v.z * iv2);
            ov.w = acc[i][3] * iv3 + (b4v.w - m4v.w * iv3);
            *(float4*)&out[(b * 49 + r) * 384 + o0] = ov;
        }
    }
}

extern "C" void kernel_launch(void* const* d_in, const int* in_sizes, int n_in,
                              void* d_out, int out_size, void* d_ws, size_t ws_size,
                              hipStream_t stream) {
    const float* x     = (const float*)d_in[0];
    const float* kv_w  = (const float*)d_in[1];
    const float* kv_g  = (const float*)d_in[2];
    const float* kv_b  = (const float*)d_in[3];
    const float* kv_m  = (const float*)d_in[4];
    const float* kv_v  = (const float*)d_in[5];
    const float* q_wp  = (const float*)d_in[6];
    const float* q_g   = (const float*)d_in[7];
    const float* q_b   = (const float*)d_in[8];
    const float* q_m   = (const float*)d_in[9];
    const float* q_v   = (const float*)d_in[10];
    const float* pw    = (const float*)d_in[11];
    const float* pg    = (const float*)d_in[12];
    const float* pb    = (const float*)d_in[13];
    const float* pm    = (const float*)d_in[14];
    const float* pv    = (const float*)d_in[15];
    const float* ab    = (const float*)d_in[16];

    // ws layout (27.5 MB, proven):
    unsigned short* ao_hi = (unsigned short*)d_ws;                 // 12544*512
    unsigned short* ao_lo = ao_hi + 12544 * 512;
    unsigned short* wb_hi = ao_lo + 12544 * 512;                   // 8*128*256
    unsigned short* wb_lo = wb_hi + 262144;
    unsigned short* pw_hi = wb_lo + 262144;                        // 384*512
    unsigned short* pw_lo = pw_hi + 196608;

    prep_split<<<1792, 256, 0, stream>>>(kv_w, q_wp, pw, wb_hi, wb_lo, pw_hi, pw_lo);

    dim3 g1(256, 4);   // block = (b, head-pair); same-b pairs share an XCD
    levit_fused_attn<<<g1, 1024, 0, stream>>>(x, wb_hi, wb_lo,
                                              kv_g, kv_b, kv_m, kv_v,
                                              q_g, q_b, q_m, q_v, ab, ao_hi, ao_lo);
    levit_proj<<<dim3(256, 4), 512, 0, stream>>>(ao_hi, ao_lo, pw_hi, pw_lo,
                                                 pg, pb, pm, pv, (float*)d_out);
}

// Round 9
// 281.225 us; speedup vs baseline: 1.7797x; 1.7797x over previous
//
#include <hip/hip_runtime.h>

// B=256, N=196, C=256, H=8, KD=32, VD=64, Q=49, R=14
#define EPS 1e-5f
#define QK_SCALE 0.17677669529663687f

typedef __attribute__((ext_vector_type(8))) short bf16x8;   // 8 bf16 = 4 VGPRs
typedef __attribute__((ext_vector_type(4))) float f32x4;

__device__ inline unsigned short bf16_rne(float f) {
    unsigned int u = __float_as_uint(f);
    u = u + 0x7FFFu + ((u >> 16) & 1u);
    return (unsigned short)(u >> 16);
}
__device__ inline float bf16_f(unsigned short s) {
    return __uint_as_float(((unsigned int)s) << 16);
}
__device__ inline void split1(float v, unsigned short& hi, unsigned short& lo) {
    hi = bf16_rne(v); lo = bf16_rne(v - bf16_f(hi));
}

// ---- packed bf16 split via v_cvt_pk_bf16_f32 (RNE, same rounding as bf16_rne)
__device__ inline unsigned int cvtpk_bf16(float a, float b) {
    unsigned int r;
    asm("v_cvt_pk_bf16_f32 %0, %1, %2" : "=v"(r) : "v"(a), "v"(b));
    return r;   // low16 = bf16(a), high16 = bf16(b)
}
__device__ inline void split2pk(float a, float b, unsigned int& h, unsigned int& l) {
    h = cvtpk_bf16(a, b);
    float ra = a - __uint_as_float(h << 16);
    float rb = b - __uint_as_float(h & 0xFFFF0000u);
    l = cvtpk_bf16(ra, rb);
}
__device__ inline void split4pk(float4 v, uint2& h, uint2& l) {
    unsigned int h01, l01, h23, l23;
    split2pk(v.x, v.y, h01, l01);
    split2pk(v.z, v.w, h23, l23);
    h.x = h01; h.y = h23; l.x = l01; l.y = l23;
}

#define MFMA16(a, b, c) __builtin_amdgcn_mfma_f32_16x16x32_bf16((a), (b), (c), 0, 0, 0)

// ---------- prep: split weights to bf16 hi/lo planes in ws
__global__ __launch_bounds__(256)
void prep_split(const float* __restrict__ kv_w, const float* __restrict__ q_w,
                const float* __restrict__ pw,
                unsigned short* __restrict__ wb_hi, unsigned short* __restrict__ wb_lo,
                unsigned short* __restrict__ pw_hi, unsigned short* __restrict__ pw_lo)
{
    int i = blockIdx.x * 256 + threadIdx.x;
    if (i < 262144) {
        int c = i & 255, j = (i >> 8) & 127, h = i >> 15;
        float v = (j < 96) ? kv_w[(h * 96 + j) * 256 + c]
                           : q_w[(h * 32 + (j - 96)) * 256 + c];
        unsigned short hi, lo; split1(v, hi, lo);
        wb_hi[i] = hi; wb_lo[i] = lo;
    } else {
        int p = i - 262144;
        if (p < 196608) {
            float v = pw[p];
            unsigned short hi, lo; split1(v, hi, lo);
            pw_hi[p] = hi; pw_lo[p] = lo;
        }
    }
}

// ---------- fused attn (R7-proven, best: ~168 us): 1024 thr (16 waves), 1 block/CU
//   split4pk before barrier-1 (barrier window = stores only); (row,8col) b128 staging.
// LDS s_big 160,384 B:  P[64][232]x2 | K[208][40]x2 | Q[52][40]x2 | V[64][232]x2
//   staging overlay (during GEMM1): x[208][72]x2 + w[128][72]x2  over P|K|Q
__global__ __launch_bounds__(1024, 4)
void levit_fused_attn(const float* __restrict__ x,
                      const unsigned short* __restrict__ wb_hi,
                      const unsigned short* __restrict__ wb_lo,
                      const float* __restrict__ kv_g, const float* __restrict__ kv_b,
                      const float* __restrict__ kv_m, const float* __restrict__ kv_v,
                      const float* __restrict__ q_g, const float* __restrict__ q_b,
                      const float* __restrict__ q_m, const float* __restrict__ q_v,
                      const float* __restrict__ attn_bias,
                      unsigned short* __restrict__ ao_hi,
                      unsigned short* __restrict__ ao_lo)
{
    __shared__ __align__(16) unsigned short s_big[80192];
    __shared__ float bias_s[196];
    __shared__ float nrm_iv[128];
    __shared__ float nrm_be[128];

    unsigned short* s_phi = s_big;             // [64][232]
    unsigned short* s_plo = s_big + 14848;
    unsigned short* s_khi = s_big + 29696;     // [208][40]
    unsigned short* s_klo = s_big + 38016;
    unsigned short* s_qhi = s_big + 46336;     // [52][40]
    unsigned short* s_qlo = s_big + 48416;
    unsigned short* s_vhi = s_big + 50496;     // [64][232] (V^T)
    unsigned short* s_vlo = s_big + 65344;
    // staging overlay (dead after GEMM1 epilogue barrier)
    unsigned short* st_xhi = s_big;            // [208][72]
    unsigned short* st_xlo = s_big + 14976;
    unsigned short* st_whi = s_big + 29952;    // [128][72]
    unsigned short* st_wlo = s_big + 39168;    // ends 48384 < 50496 (V untouched)

    const int t = threadIdx.x;
    const int b = blockIdx.x;       // linear id = b + 256*hh -> same-b heads share an XCD
    const int hh = blockIdx.y;

    const int l = t & 63;
    const int w = t >> 6;           // 16 waves
    const int rg = w & 3;           // n-tiles rt = rg + 4i (i<4, rt<13)
    const int cg = w >> 2;          // j-tiles ct = 2cg, 2cg+1
    const int lrow = l & 15;
    const int kg = (l >> 4) * 8;
    const int g4 = (l >> 4) * 4;

    // ---- staging geometry: x units (row, 8col): 1664 units over 1024 thr x 2 its
    const int x0row = t >> 3,  x0c8 = (t & 7) * 8;           // rows 0..127
    const int u1 = t + 1024;
    const int x1row = u1 >> 3, x1c8 = (u1 & 7) * 8;          // rows 128..207
    const bool xv1 = (t < 640);
    // W: 128 rows x 8 units = 1024
    const int wj = t >> 3, wc8 = (t & 7) * 8;
    const unsigned short* wsrc_hi = wb_hi + (hh * 128 + wj) * 256 + wc8;
    const unsigned short* wsrc_lo = wb_lo + (hh * 128 + wj) * 256 + wc8;
    const float* xbase = x + b * 196 * 256;
    const float4 f4z = {0.f, 0.f, 0.f, 0.f};

    float4 x0a, x0b, x1a, x1b; bf16x8 wrh, wrl;

    // prologue: issue chunk-0 loads, overlap with init
    x0a = (x0row < 196) ? *(const float4*)&xbase[x0row * 256 + x0c8]     : f4z;
    x0b = (x0row < 196) ? *(const float4*)&xbase[x0row * 256 + x0c8 + 4] : f4z;
    x1a = f4z; x1b = f4z;
    if (xv1 && x1row < 196) {
        x1a = *(const float4*)&xbase[x1row * 256 + x1c8];
        x1b = *(const float4*)&xbase[x1row * 256 + x1c8 + 4];
    }
    wrh = *(const bf16x8*)&wsrc_hi[0];
    wrl = *(const bf16x8*)&wsrc_lo[0];

    if (t < 196) bias_s[t] = attn_bias[hh * 196 + t];
    if (t >= 256 && t < 384) {      // norm params: ivv/bee per output col j
        int jj = t - 256;
        float gg, bb, mm, vv;
        if (jj < 96) { int col = hh * 96 + jj;        gg = kv_g[col]; bb = kv_b[col]; mm = kv_m[col]; vv = kv_v[col]; }
        else         { int col = hh * 32 + (jj - 96); gg = q_g[col];  bb = q_b[col];  mm = q_m[col];  vv = q_v[col]; }
        float iv = gg * rsqrtf(vv + EPS);
        nrm_iv[jj] = iv; nrm_be[jj] = bb - mm * iv;
    }
    // zero V^T pad cols 196..231 (blocks NaN: P=0 x junk)
    for (int i = t; i < 64 * 36; i += 1024) {
        int r = i / 36, c = 196 + i % 36;
        s_vhi[r * 232 + c] = 0; s_vlo[r * 232 + c] = 0;
    }

    f32x4 acc[4][2];
    #pragma unroll
    for (int i = 0; i < 4; ++i) { acc[i][0] = (f32x4){0,0,0,0}; acc[i][1] = (f32x4){0,0,0,0}; }

    // prologue store of chunk 0 (split + wide b128 stores)
    {
        uint2 ha, la, hb, lb;
        split4pk(x0a, ha, la); split4pk(x0b, hb, lb);
        *(uint4*)&st_xhi[x0row * 72 + x0c8] = (uint4){ha.x, ha.y, hb.x, hb.y};
        *(uint4*)&st_xlo[x0row * 72 + x0c8] = (uint4){la.x, la.y, lb.x, lb.y};
        if (xv1) {
            split4pk(x1a, ha, la); split4pk(x1b, hb, lb);
            *(uint4*)&st_xhi[x1row * 72 + x1c8] = (uint4){ha.x, ha.y, hb.x, hb.y};
            *(uint4*)&st_xlo[x1row * 72 + x1c8] = (uint4){la.x, la.y, lb.x, lb.y};
        }
    }
    *(bf16x8*)&st_whi[wj * 72 + wc8] = wrh;
    *(bf16x8*)&st_wlo[wj * 72 + wc8] = wrl;
    __syncthreads();

    // ---------------- GEMM1: [208 x 128] = x @ [kv_w;q_w]^T, swapped: MFMA(W, x)
    for (int s = 0; s < 4; ++s) {
        if (s < 3) {                 // issue next BK=64 chunk's loads (covered by MFMA)
            const int kcn = 64 * (s + 1);
            x0a = (x0row < 196) ? *(const float4*)&xbase[x0row * 256 + kcn + x0c8]     : f4z;
            x0b = (x0row < 196) ? *(const float4*)&xbase[x0row * 256 + kcn + x0c8 + 4] : f4z;
            x1a = f4z; x1b = f4z;
            if (xv1 && x1row < 196) {
                x1a = *(const float4*)&xbase[x1row * 256 + kcn + x1c8];
                x1b = *(const float4*)&xbase[x1row * 256 + kcn + x1c8 + 4];
            }
            wrh = *(const bf16x8*)&wsrc_hi[kcn];
            wrl = *(const bf16x8*)&wsrc_lo[kcn];
        }

        #pragma unroll
        for (int sub = 0; sub < 2; ++sub) {
            const int ko = 32 * sub + kg;
            bf16x8 wfh[2], wfl[2];
            #pragma unroll
            for (int ctl = 0; ctl < 2; ++ctl) {
                const int jr = 16 * (2 * cg + ctl) + lrow;
                wfh[ctl] = *(const bf16x8*)&st_whi[jr * 72 + ko];
                wfl[ctl] = *(const bf16x8*)&st_wlo[jr * 72 + ko];
            }
            #pragma unroll
            for (int i = 0; i < 4; ++i) {
                const int rt = rg + 4 * i;
                if (rt < 13) {                       // wave-uniform
                    const int arow = 16 * rt + lrow;
                    bf16x8 xh = *(const bf16x8*)&st_xhi[arow * 72 + ko];
                    bf16x8 xl = *(const bf16x8*)&st_xlo[arow * 72 + ko];
                    #pragma unroll
                    for (int ctl = 0; ctl < 2; ++ctl) {
                        acc[i][ctl] = MFMA16(wfh[ctl], xh, acc[i][ctl]);
                        acc[i][ctl] = MFMA16(wfh[ctl], xl, acc[i][ctl]);
                        acc[i][ctl] = MFMA16(wfl[ctl], xh, acc[i][ctl]);
                    }
                }
            }
        }

        if (s < 3) {
            // pre-split next chunk (loads arrived under the MFMA phase) -> regs
            uint4 h0, l0, h1, l1;
            {
                uint2 ha, la, hb, lb;
                split4pk(x0a, ha, la); split4pk(x0b, hb, lb);
                h0 = (uint4){ha.x, ha.y, hb.x, hb.y};
                l0 = (uint4){la.x, la.y, lb.x, lb.y};
                if (xv1) {
                    split4pk(x1a, ha, la); split4pk(x1b, hb, lb);
                    h1 = (uint4){ha.x, ha.y, hb.x, hb.y};
                    l1 = (uint4){la.x, la.y, lb.x, lb.y};
                }
            }
            __syncthreads();         // all waves done reading staging
            *(uint4*)&st_xhi[x0row * 72 + x0c8] = h0;
            *(uint4*)&st_xlo[x0row * 72 + x0c8] = l0;
            if (xv1) {
                *(uint4*)&st_xhi[x1row * 72 + x1c8] = h1;
                *(uint4*)&st_xlo[x1row * 72 + x1c8] = l1;
            }
            *(bf16x8*)&st_whi[wj * 72 + wc8] = wrh;
            *(bf16x8*)&st_wlo[wj * 72 + wc8] = wrl;
            __syncthreads();         // next buffer ready
        }
    }
    __syncthreads();   // staging dead (K/Q overlay it) -> safe to write K/Q/V

    // epilogue: norm + wide scatter.  lane holds (fixed n, j-quad j0..j0+3)
    #pragma unroll
    for (int ctl = 0; ctl < 2; ++ctl) {
        const int ct = 2 * cg + ctl;
        const int j0 = 16 * ct + g4;
        const float iv0 = nrm_iv[j0+0], be0 = nrm_be[j0+0];
        const float iv1 = nrm_iv[j0+1], be1 = nrm_be[j0+1];
        const float iv2 = nrm_iv[j0+2], be2 = nrm_be[j0+2];
        const float iv3 = nrm_iv[j0+3], be3 = nrm_be[j0+3];
        #pragma unroll
        for (int i = 0; i < 4; ++i) {
            const int rt = rg + 4 * i;
            if (rt < 13) {
                const int n = 16 * rt + lrow;
                if (n < 196) {
                    float v0 = acc[i][ctl][0] * iv0 + be0;
                    float v1 = acc[i][ctl][1] * iv1 + be1;
                    float v2 = acc[i][ctl][2] * iv2 + be2;
                    float v3 = acc[i][ctl][3] * iv3 + be3;
                    unsigned int h01, l01, h23, l23;
                    split2pk(v0, v1, h01, l01);
                    split2pk(v2, v3, h23, l23);
                    if (ct < 2) {                    // K[n][kd]: wide 8B
                        *(uint2*)&s_khi[n * 40 + j0] = (uint2){h01, h23};
                        *(uint2*)&s_klo[n * 40 + j0] = (uint2){l01, l23};
                    } else if (ct < 6) {             // V^T[vd][n]: narrow (accepted)
                        const int vd0 = j0 - 32;
                        s_vhi[(vd0+0) * 232 + n] = (unsigned short)h01;
                        s_vhi[(vd0+1) * 232 + n] = (unsigned short)(h01 >> 16);
                        s_vhi[(vd0+2) * 232 + n] = (unsigned short)h23;
                        s_vhi[(vd0+3) * 232 + n] = (unsigned short)(h23 >> 16);
                        s_vlo[(vd0+0) * 232 + n] = (unsigned short)l01;
                        s_vlo[(vd0+1) * 232 + n] = (unsigned short)(l01 >> 16);
                        s_vlo[(vd0+2) * 232 + n] = (unsigned short)l23;
                        s_vlo[(vd0+3) * 232 + n] = (unsigned short)(l23 >> 16);
                    } else {                         // Q[qi][kd]: wide 8B
                        const int a = n / 28, rem = n - 28 * a;
                        if (rem < 14 && !(rem & 1)) {
                            const int qi = a * 7 + (rem >> 1);
                            *(uint2*)&s_qhi[qi * 40 + (j0 - 96)] = (uint2){h01, h23};
                            *(uint2*)&s_qlo[qi * 40 + (j0 - 96)] = (uint2){l01, l23};
                        }
                    }
                }
            }
        }
    }
    __syncthreads();   // K/Q/V ready; P region (old staging) free

    // zero P pad cols 208..231
    for (int i = t; i < 64 * 24; i += 1024) {
        int r = i / 24, c = 208 + i % 24;
        s_phi[r * 232 + c] = 0; s_plo[r * 232 + c] = 0;
    }

    // ---------------- QK^T swapped: S^T = MFMA(K, Q); lane owns one m-column
    if (w < 4) {
        const int mt = w;
        bf16x8 qh = *(const bf16x8*)&s_qhi[(16 * mt + lrow) * 40 + kg];
        bf16x8 ql = *(const bf16x8*)&s_qlo[(16 * mt + lrow) * 40 + kg];
        f32x4 sv[13];
        #pragma unroll
        for (int nt = 0; nt < 13; ++nt) {
            bf16x8 kh = *(const bf16x8*)&s_khi[(16 * nt + lrow) * 40 + kg];
            bf16x8 kl = *(const bf16x8*)&s_klo[(16 * nt + lrow) * 40 + kg];
            f32x4 a = {0.f, 0.f, 0.f, 0.f};
            a = MFMA16(kh, qh, a);
            a = MFMA16(kh, ql, a);
            a = MFMA16(kl, qh, a);
            sv[nt] = a;
        }
        const int m = 16 * mt + lrow;          // this lane's output row
        const int mq = m < 49 ? m : 48;
        const int yq = (mq / 7) * 2, xq2 = (mq % 7) * 2;

        float lmax = -3.0e38f;
        #pragma unroll
        for (int nt = 0; nt < 13; ++nt) {
            #pragma unroll
            for (int reg = 0; reg < 4; ++reg) {
                const int n = 16 * nt + g4 + reg;
                float sc;
                if (n < 196) {
                    const int yk = n / 14, xk = n - 14 * yk;
                    int d0 = yq - yk;  d0 = d0 < 0 ? -d0 : d0;
                    int d1 = xq2 - xk; d1 = d1 < 0 ? -d1 : d1;
                    sc = sv[nt][reg] * QK_SCALE + bias_s[d0 * 14 + d1];
                } else {
                    sc = -1.0e30f;
                }
                sv[nt][reg] = sc;
                lmax = fmaxf(lmax, sc);
            }
        }
        lmax = fmaxf(lmax, __shfl_xor(lmax, 16, 64));
        lmax = fmaxf(lmax, __shfl_xor(lmax, 32, 64));
        float rsum = 0.f;
        #pragma unroll
        for (int nt = 0; nt < 13; ++nt)
            #pragma unroll
            for (int reg = 0; reg < 4; ++reg) {
                float p = __expf(sv[nt][reg] - lmax);
                sv[nt][reg] = p;
                rsum += p;
            }
        rsum += __shfl_xor(rsum, 16, 64);
        rsum += __shfl_xor(rsum, 32, 64);
        const float rinv = 1.f / rsum;
        #pragma unroll
        for (int nt = 0; nt < 13; ++nt) {      // wide row-major P writes
            unsigned int h01, l01, h23, l23;
            split2pk(sv[nt][0] * rinv, sv[nt][1] * rinv, h01, l01);
            split2pk(sv[nt][2] * rinv, sv[nt][3] * rinv, h23, l23);
            const int o = m * 232 + 16 * nt + g4;
            *(uint2*)&s_phi[o] = (uint2){h01, h23};
            *(uint2*)&s_plo[o] = (uint2){l01, l23};
        }
    }
    __syncthreads();   // P (+pads) ready

    // ---------------- PV swapped: O^T = MFMA(V^T, P); wide ao stores
    {
        const int mtv = w & 3;
        const int ntv = w >> 2;
        f32x4 pacc = {0.f, 0.f, 0.f, 0.f};
        #pragma unroll
        for (int s = 0; s < 7; ++s) {
            bf16x8 ph = *(const bf16x8*)&s_phi[(16 * mtv + lrow) * 232 + 32 * s + kg];
            bf16x8 pl = *(const bf16x8*)&s_plo[(16 * mtv + lrow) * 232 + 32 * s + kg];
            bf16x8 vh = *(const bf16x8*)&s_vhi[(16 * ntv + lrow) * 232 + 32 * s + kg];
            bf16x8 vl = *(const bf16x8*)&s_vlo[(16 * ntv + lrow) * 232 + 32 * s + kg];
            pacc = MFMA16(vh, ph, pacc);
            pacc = MFMA16(vh, pl, pacc);
            pacc = MFMA16(vl, ph, pacc);
        }
        const int m = 16 * mtv + lrow;        // lane's output row
        if (m < 49) {
            const int vd0 = 16 * ntv + g4;    // consecutive vd quad
            float hs0, hs1, hs2, hs3;
            { float v = pacc[0]; hs0 = v * fminf(fmaxf(v + 3.f, 0.f), 6.f) * (1.f/6.f); }
            { float v = pacc[1]; hs1 = v * fminf(fmaxf(v + 3.f, 0.f), 6.f) * (1.f/6.f); }
            { float v = pacc[2]; hs2 = v * fminf(fmaxf(v + 3.f, 0.f), 6.f) * (1.f/6.f); }
            { float v = pacc[3]; hs3 = v * fminf(fmaxf(v + 3.f, 0.f), 6.f) * (1.f/6.f); }
            unsigned int h01, l01, h23, l23;
            split2pk(hs0, hs1, h01, l01);
            split2pk(hs2, hs3, h23, l23);
            const int idx = ((b * 49 + m) * 8 + hh) * 64 + vd0;
            *(uint2*)&ao_hi[idx] = (uint2){h01, h23};
            *(uint2*)&ao_lo[idx] = (uint2){l01, l23};
        }
    }
}

// ---------- proj (R4-proven): pipelined reg-prefetch, A-sharing tile map, swapped MFMA
__global__ __launch_bounds__(512, 6)
void levit_proj(const unsigned short* __restrict__ ao_hi,
                const unsigned short* __restrict__ ao_lo,
                const unsigned short* __restrict__ pw_hi,
                const unsigned short* __restrict__ pw_lo,
                const float* __restrict__ pg, const float* __restrict__ pb,
                const float* __restrict__ pm, const float* __restrict__ pv,
                float* __restrict__ out)
{
    __shared__ __align__(16) unsigned short s_a[2 * 64 * 72];   // hi | lo
    __shared__ __align__(16) unsigned short s_w[2 * 96 * 72];

    unsigned short* s_ahi = s_a;          unsigned short* s_alo = s_a + 64 * 72;
    unsigned short* s_whi = s_w;          unsigned short* s_wlo = s_w + 96 * 72;

    const int t = threadIdx.x;
    const int b = blockIdx.x;
    const int cg = blockIdx.y;            // 96-col group (0..3)
    const int l = t & 63;
    const int w = t >> 6;
    const int lrow = l & 15;
    const int kg = (l >> 4) * 8;
    const int g4 = (l >> 4) * 4;

    // ---- staging geometry (fixed across kc)
    const int ar = t >> 3, ac8 = (t & 7) * 8;
    const bool aval = (ar < 49);
    const long aoff = (long)(b * 49 + ar) * 512 + ac8;
    int wpl_[3], wr_[3], wc_[3];
    #pragma unroll
    for (int it = 0; it < 3; ++it) {
        int f = t + 512 * it;
        int plane = (f >= 768), rem = plane ? f - 768 : f;
        wpl_[it] = plane; wr_[it] = rem >> 3; wc_[it] = (rem & 7) * 8;
    }

    bf16x8 pa_h = {}, pa_l = {}, pwr[3];

    // prologue: load kc=0 chunk
    if (aval) {
        pa_h = *(const bf16x8*)&ao_hi[aoff];
        pa_l = *(const bf16x8*)&ao_lo[aoff];
    }
    #pragma unroll
    for (int it = 0; it < 3; ++it) {
        const unsigned short* src = wpl_[it] ? pw_lo : pw_hi;
        pwr[it] = *(const bf16x8*)&src[(cg * 96 + wr_[it]) * 512 + wc_[it]];
    }
    *(bf16x8*)&s_ahi[ar * 72 + ac8] = pa_h;
    *(bf16x8*)&s_alo[ar * 72 + ac8] = pa_l;
    #pragma unroll
    for (int it = 0; it < 3; ++it) {
        unsigned short* dst = wpl_[it] ? s_wlo : s_whi;
        *(bf16x8*)&dst[wr_[it] * 72 + wc_[it]] = pwr[it];
    }
    __syncthreads();

    const int mt = w & 3;
    const int ntb = 3 * (w >> 2);

    f32x4 acc[3] = {{0.f,0.f,0.f,0.f},{0.f,0.f,0.f,0.f},{0.f,0.f,0.f,0.f}};

    for (int s = 0; s < 8; ++s) {
        if (s < 7) {                  // prefetch next kc chunk into regs
            const int kc = 64 * (s + 1);
            pa_h = (bf16x8){}; pa_l = (bf16x8){};
            if (aval) {
                pa_h = *(const bf16x8*)&ao_hi[aoff + kc];
                pa_l = *(const bf16x8*)&ao_lo[aoff + kc];
            }
            #pragma unroll
            for (int it = 0; it < 3; ++it) {
                const unsigned short* src = wpl_[it] ? pw_lo : pw_hi;
                pwr[it] = *(const bf16x8*)&src[(cg * 96 + wr_[it]) * 512 + kc + wc_[it]];
            }
        }

        #pragma unroll
        for (int sub = 0; sub < 2; ++sub) {
            const int ko = 32 * sub + kg;
            bf16x8 ah = *(const bf16x8*)&s_ahi[(16 * mt + lrow) * 72 + ko];
            bf16x8 al = *(const bf16x8*)&s_alo[(16 * mt + lrow) * 72 + ko];
            #pragma unroll
            for (int i = 0; i < 3; ++i) {
                const int nt = ntb + i;
                bf16x8 bh = *(const bf16x8*)&s_whi[(16 * nt + lrow) * 72 + ko];
                bf16x8 bl = *(const bf16x8*)&s_wlo[(16 * nt + lrow) * 72 + ko];
                acc[i] = MFMA16(bh, ah, acc[i]);
                acc[i] = MFMA16(bl, ah, acc[i]);
                acc[i] = MFMA16(bh, al, acc[i]);
            }
        }

        if (s < 7) {
            __syncthreads();
            *(bf16x8*)&s_ahi[ar * 72 + ac8] = pa_h;
            *(bf16x8*)&s_alo[ar * 72 + ac8] = pa_l;
            #pragma unroll
            for (int it = 0; it < 3; ++it) {
                unsigned short* dst = wpl_[it] ? s_wlo : s_whi;
                *(bf16x8*)&dst[wr_[it] * 72 + wc_[it]] = pwr[it];
            }
            __syncthreads();
        }
    }

    const int r = 16 * mt + lrow;
    if (r < 49) {
        #pragma unroll
        for (int i = 0; i < 3; ++i) {
            const int nt = ntb + i;
            const int o0 = cg * 96 + 16 * nt + g4;
            const float4 g4v = *(const float4*)&pg[o0];
            const float4 v4v = *(const float4*)&pv[o0];
            const float4 b4v = *(const float4*)&pb[o0];
            const float4 m4v = *(const float4*)&pm[o0];
            float iv0 = g4v.x * rsqrtf(v4v.x + EPS);
            float iv1 = g4v.y * rsqrtf(v4v.y + EPS);
            float iv2 = g4v.z * rsqrtf(v4v.z + EPS);
            float iv3 = g4v.w * rsqrtf(v4v.w + EPS);
            float4 ov;
            ov.x = acc[i][0] * iv0 + (b4v.x - m4v.x * iv0);
            ov.y = acc[i][1] * iv1 + (b4v.y - m4v.y * iv1);
            ov.z = acc[i][2] * iv2 + (b4v.z - m4v.z * iv2);
            ov.w = acc[i][3] * iv3 + (b4v.w - m4v.w * iv3);
            *(float4*)&out[(b * 49 + r) * 384 + o0] = ov;
        }
    }
}

extern "C" void kernel_launch(void* const* d_in, const int* in_sizes, int n_in,
                              void* d_out, int out_size, void* d_ws, size_t ws_size,
                              hipStream_t stream) {
    const float* x     = (const float*)d_in[0];
    const float* kv_w  = (const float*)d_in[1];
    const float* kv_g  = (const float*)d_in[2];
    const float* kv_b  = (const float*)d_in[3];
    const float* kv_m  = (const float*)d_in[4];
    const float* kv_v  = (const float*)d_in[5];
    const float* q_wp  = (const float*)d_in[6];
    const float* q_g   = (const float*)d_in[7];
    const float* q_b   = (const float*)d_in[8];
    const float* q_m   = (const float*)d_in[9];
    const float* q_v   = (const float*)d_in[10];
    const float* pw    = (const float*)d_in[11];
    const float* pg    = (const float*)d_in[12];
    const float* pb    = (const float*)d_in[13];
    const float* pm    = (const float*)d_in[14];
    const float* pv    = (const float*)d_in[15];
    const float* ab    = (const float*)d_in[16];

    // ws layout (27.5 MB, proven):
    unsigned short* ao_hi = (unsigned short*)d_ws;                 // 12544*512
    unsigned short* ao_lo = ao_hi + 12544 * 512;
    unsigned short* wb_hi = ao_lo + 12544 * 512;                   // 8*128*256
    unsigned short* wb_lo = wb_hi + 262144;
    unsigned short* pw_hi = wb_lo + 262144;                        // 384*512
    unsigned short* pw_lo = pw_hi + 196608;

    prep_split<<<1792, 256, 0, stream>>>(kv_w, q_wp, pw, wb_hi, wb_lo, pw_hi, pw_lo);

    dim3 g1(256, 8);   // linear id = b + 256*hh -> same-b heads share an XCD
    levit_fused_attn<<<g1, 1024, 0, stream>>>(x, wb_hi, wb_lo,
                                              kv_g, kv_b, kv_m, kv_v,
                                              q_g, q_b, q_m, q_v, ab, ao_hi, ao_lo);
    levit_proj<<<dim3(256, 4), 512, 0, stream>>>(ao_hi, ao_lo, pw_hi, pw_lo,
                                                 pg, pb, pm, pv, (float*)d_out);
}